// Round 14
// baseline (179.316 us; speedup 1.0000x reference)
//
#include <hip/hip_runtime.h>

// ---------------------------------------------------------------------------
// RoBERTa self-attention: QKV projection (bf16 MFMA) + flash attention.
// B=4, S=2048, D=1024, H=16, HD=64.  fp32 in/out, bf16 internal, fp32 acc.
// R14: attn waves own 64 q (2 B-frags) instead of 32. K-frags read ONCE per
//      tile and reused for both q-frags; V-frags once per sl for both ->
//      per-q LDS traffic -33% (R13 showed VALU moves are null; DS/issue per
//      q is the remaining lever). Two independent qf chains also double
//      in-wave ILP to offset 2-waves/SIMD occupancy (VGPR ~240).
// ---------------------------------------------------------------------------

typedef __bf16 bf16;
typedef bf16  bf16x8 __attribute__((ext_vector_type(8)));
typedef bf16  bf16x4 __attribute__((ext_vector_type(4)));
typedef float f32x4  __attribute__((ext_vector_type(4)));
typedef float f32x16 __attribute__((ext_vector_type(16)));
typedef int   i32x2  __attribute__((ext_vector_type(2)));

#define MFMA16(A, B, C) __builtin_amdgcn_mfma_f32_16x16x32_bf16((A), (B), (C), 0, 0, 0)
#define MFMA32(A, B, C) __builtin_amdgcn_mfma_f32_32x32x16_bf16((A), (B), (C), 0, 0, 0)

constexpr int BB = 4, SS = 2048, DD = 1024, HH = 16, HD = 64;
constexpr int NX = BB * SS * DD;   // 8388608
constexpr int NW = DD * DD;        // 1048576
constexpr float SCALE = 0.125f;    // 1/sqrt(64)
constexpr float LOG2E = 1.44269504088896f;
constexpr float SCALE_LOG2E = SCALE * LOG2E;

__device__ __forceinline__ float fast_exp2(float x) {
#if __has_builtin(__builtin_amdgcn_exp2f)
  return __builtin_amdgcn_exp2f(x);
#else
  float r;
  asm("v_exp_f32 %0, %1\n\ts_nop 1" : "=v"(r) : "v"(x));
  return r;
#endif
}

__device__ __forceinline__ bf16x8 cvt8(f32x4 a, f32x4 b) {
  bf16x8 r;
  r[0] = (bf16)a[0]; r[1] = (bf16)a[1]; r[2] = (bf16)a[2]; r[3] = (bf16)a[3];
  r[4] = (bf16)b[0]; r[5] = (bf16)b[1]; r[6] = (bf16)b[2]; r[7] = (bf16)b[3];
  return r;
}

__device__ __forceinline__ unsigned pack2(float lo, float hi) {
  union { bf16 h[2]; unsigned u; } r;
  r.h[0] = (bf16)lo; r.h[1] = (bf16)hi;
  return r.u;
}

// Exchange across the wave's 32-lane halves (verified R7).
__device__ __forceinline__ void swap32(unsigned &a, unsigned &b) {
#if __has_builtin(__builtin_amdgcn_permlane32_swap)
  i32x2 r = __builtin_amdgcn_permlane32_swap((int)a, (int)b, false, false);
  a = (unsigned)r[0]; b = (unsigned)r[1];
#else
  int hi = (int)((threadIdx.x >> 5) & 1);
  unsigned xa = (unsigned)__shfl_xor((int)a, 32);
  unsigned xb = (unsigned)__shfl_xor((int)b, 32);
  unsigned na = hi ? xb : a;
  unsigned nb = hi ? b  : xa;
  a = na; b = nb;
#endif
}

// async global -> LDS, 16B per lane (dest = uniform base + lane*16)
__device__ __forceinline__ void gload_lds16(const bf16* g, bf16* l) {
  __builtin_amdgcn_global_load_lds(
      (const __attribute__((address_space(1))) void*)g,
      (__attribute__((address_space(3))) void*)l, 16, 0, 0);
}

// explicit drain of outstanding global_load_lds / ds ops (race fix, R12)
__device__ __forceinline__ void drain_mem() {
  asm volatile("s_waitcnt vmcnt(0) lgkmcnt(0)" ::: "memory");
}

// ---------------------------------------------------------------------------
// Kernel 0: fp32 -> bf16 convert of X and Wq|Wk|Wv (into d_out scratch).
// ---------------------------------------------------------------------------
__global__ __launch_bounds__(256) void cvt_bf16(
    const float* __restrict__ X,  const float* __restrict__ Wq,
    const float* __restrict__ Wk, const float* __restrict__ Wv,
    bf16* __restrict__ Xb, bf16* __restrict__ Wb) {
  int i = (blockIdx.x * 256 + threadIdx.x) * 8;
  const float* src; bf16* dst; int off;
  if (i < NX)               { src = X;  dst = Xb;          off = i; }
  else if (i < NX + NW)     { src = Wq; dst = Wb;          off = i - NX; }
  else if (i < NX + 2 * NW) { src = Wk; dst = Wb + NW;     off = i - NX - NW; }
  else                      { src = Wv; dst = Wb + 2 * NW; off = i - NX - 2 * NW; }
  f32x4 a = *(const f32x4*)(src + off);
  f32x4 b = *(const f32x4*)(src + off + 4);
  *(bf16x8*)(dst + off) = cvt8(a, b);
}

// ---------------------------------------------------------------------------
// Kernel 1: Y = Xb @ Wb[z]^T + b, bf16 in, bf16 out (m97 structure).
//   z==0 -> Q [8192,1024] PRE-SCALED by SCALE*LOG2E;  z==1 -> K;
//   z==2 -> V transposed per-head.
// ---------------------------------------------------------------------------
__global__ __launch_bounds__(256, 2) void qkv_gemm(
    const bf16* __restrict__ Xb, const bf16* __restrict__ Wb,
    const float* __restrict__ bq, const float* __restrict__ bk,
    const float* __restrict__ bv,
    bf16* __restrict__ Qo, bf16* __restrict__ Ko, bf16* __restrict__ Vt) {
  const int z = blockIdx.z;
  const bf16*  W    = Wb + (size_t)z * NW;
  const float* bias = (z == 0) ? bq : (z == 1) ? bk : bv;
  const float  osc  = (z == 0) ? SCALE_LOG2E : 1.0f;  // Q pre-scale

  __shared__ bf16 As[128 * 64];
  __shared__ bf16 Bs[128 * 64];

  const int tid  = threadIdx.x;
  const int lane = tid & 63;
  const int w    = tid >> 6;
  const int wr   = w >> 1, wc = w & 1;
  const int m0   = blockIdx.x * 128;
  const int n0   = blockIdx.y * 128;
  const int c    = lane & 15, g = lane >> 4;

  const int lr  = lane >> 3;
  const int lcs = ((lane & 7) ^ lr) * 8;
  const bf16* aSrc = Xb + (size_t)(m0 + w * 32 + lr) * DD + lcs;
  const bf16* bSrc = W  + (size_t)(n0 + w * 32 + lr) * DD + lcs;
  bf16* aDst = &As[(w * 32) * 64];
  bf16* bDst = &Bs[(w * 32) * 64];

  f32x4 acc[4][4];
#pragma unroll
  for (int i = 0; i < 4; ++i)
#pragma unroll
    for (int j = 0; j < 4; ++j) acc[i][j] = f32x4{0.f, 0.f, 0.f, 0.f};

  for (int k0 = 0; k0 < DD; k0 += 64) {
    __syncthreads();   // previous compute done (WAR on LDS)
#pragma unroll
    for (int cc = 0; cc < 4; ++cc) {
      gload_lds16(aSrc + (size_t)cc * 8 * DD + k0, aDst + cc * 512);
      gload_lds16(bSrc + (size_t)cc * 8 * DD + k0, bDst + cc * 512);
    }
    drain_mem();
    __syncthreads();   // tile ready

#pragma unroll
    for (int kk = 0; kk < 64; kk += 32) {
      bf16x8 af[4], bfr[4];
#pragma unroll
      for (int m = 0; m < 4; ++m) {
        int row = wr * 64 + m * 16 + c;
        af[m] = *(const bf16x8*)(&As[row * 64 + (((kk >> 3) + g) ^ (row & 7)) * 8]);
      }
#pragma unroll
      for (int n = 0; n < 4; ++n) {
        int row = wc * 64 + n * 16 + c;
        bfr[n] = *(const bf16x8*)(&Bs[row * 64 + (((kk >> 3) + g) ^ (row & 7)) * 8]);
      }
#pragma unroll
      for (int m = 0; m < 4; ++m)
#pragma unroll
        for (int n = 0; n < 4; ++n)
          acc[m][n] = MFMA16(af[m], bfr[n], acc[m][n]);
    }
  }

#pragma unroll
  for (int n = 0; n < 4; ++n) {
    int colg = n0 + wc * 64 + n * 16 + c;
    float bv_ = bias[colg];
#pragma unroll
    for (int m = 0; m < 4; ++m) {
      int rowg = m0 + wr * 64 + m * 16 + g * 4;
      f32x4 a = acc[m][n];
      if (z < 2) {
        bf16* dst = (z == 0) ? Qo : Ko;
#pragma unroll
        for (int j = 0; j < 4; ++j)
          dst[(size_t)(rowg + j) * DD + colg] = (bf16)((a[j] + bv_) * osc);
      } else {
        int bi = rowg >> 11, s = rowg & 2047;
        int hh = colg >> 6, dd = colg & 63;
        bf16x4 pv;
#pragma unroll
        for (int j = 0; j < 4; ++j) pv[j] = (bf16)(a[j] + bv_);
        *(bf16x4*)(&Vt[(((size_t)bi * HH + hh) * HD + dd) * SS + s]) = pv;
      }
    }
  }
}

// ---------------------------------------------------------------------------
// Kernel 2: flash attention, 32x32x16 MFMA. Grid (B*H, S/256), 4 waves.
// Wave w owns q rows [qb*256 + w*64, +64) as TWO 32-q fragments (qf0/qf1).
// K frags loaded once per tile, reused by both qf; V frags once per sl.
// LDS map: Ks[2] @0, Vs[2] @16384, Ms @32768 (mask*LOG2E as QK^T C-operand).
// lsum via ones-MFMA (accL*, verified R13). Drain before each barrier (R12).
// ---------------------------------------------------------------------------
__global__ __launch_bounds__(256) void attn(
    const bf16* __restrict__ Q,   // [B*S, D] (pre-scaled)
    const bf16* __restrict__ K,   // [B*S, D]
    const bf16* __restrict__ Vt,  // [(b*16+h)*64 + d][S]
    const float* __restrict__ mask,  // [B, S] additive
    float* __restrict__ out) {       // [B, S, D] fp32
  __shared__ __align__(16) char smem[40960];

  const int bh = blockIdx.x;  // 0..63
  const int qb = blockIdx.y;  // 0..7
  const int b = bh >> 4, h = bh & 15;
  const int tid = threadIdx.x;
  const int lane = tid & 63;
  const int w = tid >> 6;
  const int l31 = lane & 31, hi = lane >> 5;
  const int hi4 = hi * 4, hi8 = hi * 8;
  const int qg0 = qb * 256 + w * 64 + l31;  // qf0 q row
  // qf1 q row = qg0 + 32

  const bf16* qptr0 = Q + ((size_t)(b * SS + qg0)) * DD + h * HD;
  bf16x8 qB0[4], qB1[4];
#pragma unroll
  for (int ks = 0; ks < 4; ++ks) {
    qB0[ks] = *(const bf16x8*)(qptr0 + ks * 16 + hi8);
    qB1[ks] = *(const bf16x8*)(qptr0 + (size_t)32 * DD + ks * 16 + hi8);
  }

  // ones A-frag for the lsum MFMA
  bf16x8 ones;
#pragma unroll
  for (int i = 0; i < 8; ++i) ones[i] = (bf16)1.0f;

  // 4 shared fragment offsets (bytes): row part + XOR-permuted chunk.
  int off[4];
#pragma unroll
  for (int x = 0; x < 4; ++x)
    off[x] = l31 * 128 + (((2 * x + hi) ^ (l31 & 7)) * 16);

  // staging geometry (global_load_lds): 8 rows x 8 slots per call.
  const int lr  = lane >> 3;
  const int lc  = ((lane & 7) ^ lr) * 8;   // pre-swizzled source chunk
  const int r0  = w * 16 + lr;
  const bf16* kpA = K  + ((size_t)b * SS + r0) * DD + h * HD + lc;
  const bf16* kpB = kpA + (size_t)8 * DD;
  const bf16* vpA = Vt + ((size_t)bh * HD + r0) * SS + lc;
  const bf16* vpB = vpA + (size_t)8 * SS;
  bf16* kD0 = (bf16*)(smem + w * 2048);
  bf16* vD0 = (bf16*)(smem + 16384 + w * 2048);

  f32x16 acc00 = {}, acc01 = {}, acc10 = {}, acc11 = {};  // [qf][db]
  f32x16 accL0 = {}, accL1 = {};

  // ---- prologue: mask*LOG2E -> Ms; stage tile 0 into buf 0 ----
  {
    const float* mbase = mask + b * SS;
    f32x4 m0 = *(const f32x4*)(mbase + tid * 8);
    f32x4 m1 = *(const f32x4*)(mbase + tid * 8 + 4);
    *(f32x4*)(smem + 32768 + tid * 32)      = m0 * LOG2E;
    *(f32x4*)(smem + 32768 + tid * 32 + 16) = m1 * LOG2E;
  }
  gload_lds16(kpA, kD0);
  gload_lds16(kpB, kD0 + 512);
  gload_lds16(vpA, vD0);
  gload_lds16(vpB, vD0 + 512);
  kpA += (size_t)64 * DD; kpB += (size_t)64 * DD;
  vpA += 64;              vpB += 64;
  drain_mem();
  __syncthreads();

  for (int t2 = 0; t2 < 16; ++t2) {
#pragma unroll
    for (int half = 0; half < 2; ++half) {
      const int t = t2 * 2 + half;
      const bool last = (t == 31);

      // ---- prefetch tile t+1 into buffer half^1 (async) ----
      if (!last) {
        bf16* kD = (bf16*)(smem + (half ^ 1) * 8192 + w * 2048);
        bf16* vD = (bf16*)(smem + 16384 + (half ^ 1) * 8192 + w * 2048);
        gload_lds16(kpA, kD);
        gload_lds16(kpB, kD + 512);
        gload_lds16(vpA, vD);
        gload_lds16(vpB, vD + 512);
        kpA += (size_t)64 * DD; kpB += (size_t)64 * DD;
        vpA += 64;              vpB += 64;
      }

      // ---- K frags once (shared by qf0/qf1) ----
      bf16x8 ka[2][4];
#pragma unroll
      for (int kvb = 0; kvb < 2; ++kvb)
#pragma unroll
        for (int ks = 0; ks < 4; ++ks)
          ka[kvb][ks] = *(const bf16x8*)(smem + off[ks] + kvb * 4096 + half * 8192);

      const char* mb = smem + (t * 256 + hi4 * 4);
      bf16x8 pP0[4], pP1[4];   // packed P per kv-slice, per qf

      // ==== qf0: QKT -> exp -> pack ====
      {
        union { f32x16 v; f32x4 q[4]; } st[2];
#pragma unroll
        for (int kvb = 0; kvb < 2; ++kvb)
#pragma unroll
          for (int rg = 0; rg < 4; ++rg)
            st[kvb].q[rg] = *(const f32x4*)(mb + 32768 + kvb * 128 + rg * 32);
        __builtin_amdgcn_s_setprio(1);
#pragma unroll
        for (int kvb = 0; kvb < 2; ++kvb)
#pragma unroll
          for (int ks = 0; ks < 4; ++ks)
            st[kvb].v = MFMA32(ka[kvb][ks], qB0[ks], st[kvb].v);
        __builtin_amdgcn_s_setprio(0);
#pragma unroll
        for (int kvb = 0; kvb < 2; ++kvb)
#pragma unroll
          for (int r = 0; r < 16; ++r)
            st[kvb].v[r] = fast_exp2(st[kvb].v[r]);
#pragma unroll
        for (int kvb = 0; kvb < 2; ++kvb)
#pragma unroll
          for (int s2 = 0; s2 < 2; ++s2) {
            unsigned L0 = pack2(st[kvb].v[8 * s2 + 0], st[kvb].v[8 * s2 + 1]);
            unsigned L1 = pack2(st[kvb].v[8 * s2 + 2], st[kvb].v[8 * s2 + 3]);
            unsigned H0 = pack2(st[kvb].v[8 * s2 + 4], st[kvb].v[8 * s2 + 5]);
            unsigned H1 = pack2(st[kvb].v[8 * s2 + 6], st[kvb].v[8 * s2 + 7]);
            swap32(L0, H0);
            swap32(L1, H1);
            union { unsigned u[4]; bf16x8 v; } pb;
            pb.u[0] = L0; pb.u[1] = L1; pb.u[2] = H0; pb.u[3] = H1;
            pP0[kvb * 2 + s2] = pb.v;
          }
      }

      // ==== qf1: QKT -> exp -> pack ====
      {
        union { f32x16 v; f32x4 q[4]; } st[2];
#pragma unroll
        for (int kvb = 0; kvb < 2; ++kvb)
#pragma unroll
          for (int rg = 0; rg < 4; ++rg)
            st[kvb].q[rg] = *(const f32x4*)(mb + 32768 + kvb * 128 + rg * 32);
        __builtin_amdgcn_s_setprio(1);
#pragma unroll
        for (int kvb = 0; kvb < 2; ++kvb)
#pragma unroll
          for (int ks = 0; ks < 4; ++ks)
            st[kvb].v = MFMA32(ka[kvb][ks], qB1[ks], st[kvb].v);
        __builtin_amdgcn_s_setprio(0);
#pragma unroll
        for (int kvb = 0; kvb < 2; ++kvb)
#pragma unroll
          for (int r = 0; r < 16; ++r)
            st[kvb].v[r] = fast_exp2(st[kvb].v[r]);
#pragma unroll
        for (int kvb = 0; kvb < 2; ++kvb)
#pragma unroll
          for (int s2 = 0; s2 < 2; ++s2) {
            unsigned L0 = pack2(st[kvb].v[8 * s2 + 0], st[kvb].v[8 * s2 + 1]);
            unsigned L1 = pack2(st[kvb].v[8 * s2 + 2], st[kvb].v[8 * s2 + 3]);
            unsigned H0 = pack2(st[kvb].v[8 * s2 + 4], st[kvb].v[8 * s2 + 5]);
            unsigned H1 = pack2(st[kvb].v[8 * s2 + 6], st[kvb].v[8 * s2 + 7]);
            swap32(L0, H0);
            swap32(L1, H1);
            union { unsigned u[4]; bf16x8 v; } pb;
            pb.u[0] = L0; pb.u[1] = L1; pb.u[2] = H0; pb.u[3] = H1;
            pP1[kvb * 2 + s2] = pb.v;
          }
      }

      // ==== PV + lsum: V frags once per sl, used by both qf ====
      __builtin_amdgcn_s_setprio(1);
#pragma unroll
      for (int sl = 0; sl < 4; ++sl) {
        bf16x8 va0 = *(const bf16x8*)(smem + 16384 + off[sl] + half * 8192);
        bf16x8 va1 = *(const bf16x8*)(smem + 16384 + off[sl] + 4096 + half * 8192);
        acc00 = MFMA32(va0, pP0[sl], acc00);
        acc01 = MFMA32(va1, pP0[sl], acc01);
        accL0 = MFMA32(ones, pP0[sl], accL0);
        acc10 = MFMA32(va0, pP1[sl], acc10);
        acc11 = MFMA32(va1, pP1[sl], acc11);
        accL1 = MFMA32(ones, pP1[sl], accL1);
      }
      __builtin_amdgcn_s_setprio(0);

      drain_mem();       // prefetched gload_lds writes landed
      __syncthreads();
    }
  }

  // ---- epilogue: accL*[0] = full lsum per q column ----
  const float inv0 = 1.0f / accL0[0];
  const float inv1 = 1.0f / accL1[0];

  float* op0 = out + ((size_t)(b * SS + qg0)) * DD + h * HD;
  float* op1 = op0 + (size_t)32 * DD;
#pragma unroll
  for (int db = 0; db < 2; ++db)
#pragma unroll
    for (int rg = 0; rg < 4; ++rg) {
      const f32x16& a0 = db ? acc01 : acc00;
      const f32x16& a1 = db ? acc11 : acc10;
      f32x4 v0, v1;
#pragma unroll
      for (int j = 0; j < 4; ++j) {
        v0[j] = a0[rg * 4 + j] * inv0;
        v1[j] = a1[rg * 4 + j] * inv1;
      }
      *(f32x4*)(op0 + db * 32 + rg * 8 + hi4) = v0;
      *(f32x4*)(op1 + db * 32 + rg * 8 + hi4) = v1;
    }
}

// ---------------------------------------------------------------------------
extern "C" void kernel_launch(void* const* d_in, const int* in_sizes, int n_in,
                              void* d_out, int out_size, void* d_ws, size_t ws_size,
                              hipStream_t stream) {
  const float* X    = (const float*)d_in[0];
  const float* mask = (const float*)d_in[1];
  const float* Wq   = (const float*)d_in[2];
  const float* bq   = (const float*)d_in[3];
  const float* Wk   = (const float*)d_in[4];
  const float* bk   = (const float*)d_in[5];
  const float* Wv   = (const float*)d_in[6];
  const float* bv   = (const float*)d_in[7];

  // workspace: Q | K | Vt (bf16, 16 MiB each)
  bf16* Qw = (bf16*)d_ws;
  bf16* Kw = Qw + (size_t)NX;
  bf16* Vt = Kw + (size_t)NX;
  // bf16 scratch for converted inputs lives in d_out (attn overwrites later).
  bf16* Xb = (bf16*)d_out;            // 16 MiB
  bf16* Wb = Xb + (size_t)NX;         // 6 MiB (Wq|Wk|Wv)

  cvt_bf16<<<(NX + 3 * NW) / 2048, 256, 0, stream>>>(X, Wq, Wk, Wv, Xb, Wb);

  dim3 g1((BB * SS) / 128, DD / 128, 3);
  qkv_gemm<<<g1, 256, 0, stream>>>(Xb, Wb, bq, bk, bv, Qw, Kw, Vt);

  dim3 g2(BB * HH, SS / 256);  // 64 x 8
  attn<<<g2, 256, 0, stream>>>(Qw, Kw, Vt, mask, (float*)d_out);
}

// Round 15
// 161.979 us; speedup vs baseline: 1.1070x; 1.1070x over previous
//
#include <hip/hip_runtime.h>

// ---------------------------------------------------------------------------
// RoBERTa self-attention: QKV projection (bf16 MFMA) + flash attention.
// B=4, S=2048, D=1024, H=16, HD=64.  fp32 in/out, bf16 internal, fp32 acc.
// R15: exact revert to R13 (161.5us, twice-validated). R14's 64q/wave
//      halved occupancy (16->8 waves/CU) and regressed 108.7->128.8us:
//      this structure's balance point is 32q/wave + 16 waves/CU.
//      R13 = drain-hardened prefetch (R12) + const-folded softmax (R10)
//      + lsum-on-MFMA (accL) + mask-as-C-operand + permlane repack.
// ---------------------------------------------------------------------------

typedef __bf16 bf16;
typedef bf16  bf16x8 __attribute__((ext_vector_type(8)));
typedef bf16  bf16x4 __attribute__((ext_vector_type(4)));
typedef float f32x4  __attribute__((ext_vector_type(4)));
typedef float f32x16 __attribute__((ext_vector_type(16)));
typedef int   i32x2  __attribute__((ext_vector_type(2)));

#define MFMA16(A, B, C) __builtin_amdgcn_mfma_f32_16x16x32_bf16((A), (B), (C), 0, 0, 0)
#define MFMA32(A, B, C) __builtin_amdgcn_mfma_f32_32x32x16_bf16((A), (B), (C), 0, 0, 0)

constexpr int BB = 4, SS = 2048, DD = 1024, HH = 16, HD = 64;
constexpr int NX = BB * SS * DD;   // 8388608
constexpr int NW = DD * DD;        // 1048576
constexpr float SCALE = 0.125f;    // 1/sqrt(64)
constexpr float LOG2E = 1.44269504088896f;
constexpr float SCALE_LOG2E = SCALE * LOG2E;

__device__ __forceinline__ float fast_exp2(float x) {
#if __has_builtin(__builtin_amdgcn_exp2f)
  return __builtin_amdgcn_exp2f(x);
#else
  float r;
  asm("v_exp_f32 %0, %1\n\ts_nop 1" : "=v"(r) : "v"(x));
  return r;
#endif
}

__device__ __forceinline__ bf16x8 cvt8(f32x4 a, f32x4 b) {
  bf16x8 r;
  r[0] = (bf16)a[0]; r[1] = (bf16)a[1]; r[2] = (bf16)a[2]; r[3] = (bf16)a[3];
  r[4] = (bf16)b[0]; r[5] = (bf16)b[1]; r[6] = (bf16)b[2]; r[7] = (bf16)b[3];
  return r;
}

__device__ __forceinline__ unsigned pack2(float lo, float hi) {
  union { bf16 h[2]; unsigned u; } r;
  r.h[0] = (bf16)lo; r.h[1] = (bf16)hi;
  return r.u;
}

// Exchange across the wave's 32-lane halves (verified R7).
__device__ __forceinline__ void swap32(unsigned &a, unsigned &b) {
#if __has_builtin(__builtin_amdgcn_permlane32_swap)
  i32x2 r = __builtin_amdgcn_permlane32_swap((int)a, (int)b, false, false);
  a = (unsigned)r[0]; b = (unsigned)r[1];
#else
  int hi = (int)((threadIdx.x >> 5) & 1);
  unsigned xa = (unsigned)__shfl_xor((int)a, 32);
  unsigned xb = (unsigned)__shfl_xor((int)b, 32);
  unsigned na = hi ? xb : a;
  unsigned nb = hi ? b  : xa;
  a = na; b = nb;
#endif
}

// async global -> LDS, 16B per lane (dest = uniform base + lane*16)
__device__ __forceinline__ void gload_lds16(const bf16* g, bf16* l) {
  __builtin_amdgcn_global_load_lds(
      (const __attribute__((address_space(1))) void*)g,
      (__attribute__((address_space(3))) void*)l, 16, 0, 0);
}

// explicit drain of outstanding global_load_lds / ds ops (race fix, R12 --
// without this the post-timing revalidation diverged in R11)
__device__ __forceinline__ void drain_mem() {
  asm volatile("s_waitcnt vmcnt(0) lgkmcnt(0)" ::: "memory");
}

// ---------------------------------------------------------------------------
// Kernel 0: fp32 -> bf16 convert of X and Wq|Wk|Wv (into d_out scratch).
// ---------------------------------------------------------------------------
__global__ __launch_bounds__(256) void cvt_bf16(
    const float* __restrict__ X,  const float* __restrict__ Wq,
    const float* __restrict__ Wk, const float* __restrict__ Wv,
    bf16* __restrict__ Xb, bf16* __restrict__ Wb) {
  int i = (blockIdx.x * 256 + threadIdx.x) * 8;
  const float* src; bf16* dst; int off;
  if (i < NX)               { src = X;  dst = Xb;          off = i; }
  else if (i < NX + NW)     { src = Wq; dst = Wb;          off = i - NX; }
  else if (i < NX + 2 * NW) { src = Wk; dst = Wb + NW;     off = i - NX - NW; }
  else                      { src = Wv; dst = Wb + 2 * NW; off = i - NX - 2 * NW; }
  f32x4 a = *(const f32x4*)(src + off);
  f32x4 b = *(const f32x4*)(src + off + 4);
  *(bf16x8*)(dst + off) = cvt8(a, b);
}

// ---------------------------------------------------------------------------
// Kernel 1: Y = Xb @ Wb[z]^T + b, bf16 in, bf16 out (m97 structure).
//   z==0 -> Q [8192,1024] PRE-SCALED by SCALE*LOG2E;  z==1 -> K;
//   z==2 -> V transposed per-head.
// ---------------------------------------------------------------------------
__global__ __launch_bounds__(256, 2) void qkv_gemm(
    const bf16* __restrict__ Xb, const bf16* __restrict__ Wb,
    const float* __restrict__ bq, const float* __restrict__ bk,
    const float* __restrict__ bv,
    bf16* __restrict__ Qo, bf16* __restrict__ Ko, bf16* __restrict__ Vt) {
  const int z = blockIdx.z;
  const bf16*  W    = Wb + (size_t)z * NW;
  const float* bias = (z == 0) ? bq : (z == 1) ? bk : bv;
  const float  osc  = (z == 0) ? SCALE_LOG2E : 1.0f;  // Q pre-scale

  __shared__ bf16 As[128 * 64];
  __shared__ bf16 Bs[128 * 64];

  const int tid  = threadIdx.x;
  const int lane = tid & 63;
  const int w    = tid >> 6;
  const int wr   = w >> 1, wc = w & 1;
  const int m0   = blockIdx.x * 128;
  const int n0   = blockIdx.y * 128;
  const int c    = lane & 15, g = lane >> 4;

  const int lr  = lane >> 3;
  const int lcs = ((lane & 7) ^ lr) * 8;
  const bf16* aSrc = Xb + (size_t)(m0 + w * 32 + lr) * DD + lcs;
  const bf16* bSrc = W  + (size_t)(n0 + w * 32 + lr) * DD + lcs;
  bf16* aDst = &As[(w * 32) * 64];
  bf16* bDst = &Bs[(w * 32) * 64];

  f32x4 acc[4][4];
#pragma unroll
  for (int i = 0; i < 4; ++i)
#pragma unroll
    for (int j = 0; j < 4; ++j) acc[i][j] = f32x4{0.f, 0.f, 0.f, 0.f};

  for (int k0 = 0; k0 < DD; k0 += 64) {
    __syncthreads();   // previous compute done (WAR on LDS)
#pragma unroll
    for (int cc = 0; cc < 4; ++cc) {
      gload_lds16(aSrc + (size_t)cc * 8 * DD + k0, aDst + cc * 512);
      gload_lds16(bSrc + (size_t)cc * 8 * DD + k0, bDst + cc * 512);
    }
    drain_mem();
    __syncthreads();   // tile ready

#pragma unroll
    for (int kk = 0; kk < 64; kk += 32) {
      bf16x8 af[4], bfr[4];
#pragma unroll
      for (int m = 0; m < 4; ++m) {
        int row = wr * 64 + m * 16 + c;
        af[m] = *(const bf16x8*)(&As[row * 64 + (((kk >> 3) + g) ^ (row & 7)) * 8]);
      }
#pragma unroll
      for (int n = 0; n < 4; ++n) {
        int row = wc * 64 + n * 16 + c;
        bfr[n] = *(const bf16x8*)(&Bs[row * 64 + (((kk >> 3) + g) ^ (row & 7)) * 8]);
      }
#pragma unroll
      for (int m = 0; m < 4; ++m)
#pragma unroll
        for (int n = 0; n < 4; ++n)
          acc[m][n] = MFMA16(af[m], bfr[n], acc[m][n]);
    }
  }

#pragma unroll
  for (int n = 0; n < 4; ++n) {
    int colg = n0 + wc * 64 + n * 16 + c;
    float bv_ = bias[colg];
#pragma unroll
    for (int m = 0; m < 4; ++m) {
      int rowg = m0 + wr * 64 + m * 16 + g * 4;
      f32x4 a = acc[m][n];
      if (z < 2) {
        bf16* dst = (z == 0) ? Qo : Ko;
#pragma unroll
        for (int j = 0; j < 4; ++j)
          dst[(size_t)(rowg + j) * DD + colg] = (bf16)((a[j] + bv_) * osc);
      } else {
        int bi = rowg >> 11, s = rowg & 2047;
        int hh = colg >> 6, dd = colg & 63;
        bf16x4 pv;
#pragma unroll
        for (int j = 0; j < 4; ++j) pv[j] = (bf16)(a[j] + bv_);
        *(bf16x4*)(&Vt[(((size_t)bi * HH + hh) * HD + dd) * SS + s]) = pv;
      }
    }
  }
}

// ---------------------------------------------------------------------------
// Kernel 2: flash attention, 32x32x16 MFMA. Grid (B*H, S/128), 4 waves.
// LDS map: Ks[2] @0 (2x8KB), Vs[2] @16384, Ms @32768 (8KB, mask*LOG2E as
// QK^T C-operand; Q pre-scaled -> MFMA out = exp2 argument directly).
// lsum via ones-MFMA into accL: every reg of accL = per-q-column sum of P
// (col = lane&31 for BOTH hi halves), so accL[0] is the lane's full lsum.
// Explicit vmcnt/lgkm drain before each tile barrier (race hardening).
// ---------------------------------------------------------------------------
__global__ __launch_bounds__(256) void attn(
    const bf16* __restrict__ Q,   // [B*S, D] (pre-scaled)
    const bf16* __restrict__ K,   // [B*S, D]
    const bf16* __restrict__ Vt,  // [(b*16+h)*64 + d][S]
    const float* __restrict__ mask,  // [B, S] additive
    float* __restrict__ out) {       // [B, S, D] fp32
  __shared__ __align__(16) char smem[40960];

  const int bh = blockIdx.x;  // 0..63
  const int qb = blockIdx.y;  // 0..15
  const int b = bh >> 4, h = bh & 15;
  const int tid = threadIdx.x;
  const int lane = tid & 63;
  const int w = tid >> 6;
  const int l31 = lane & 31, hi = lane >> 5;
  const int hi4 = hi * 4, hi8 = hi * 8;
  const int qg = qb * 128 + w * 32 + l31;  // this lane's q row

  const bf16* qptr = Q + ((size_t)(b * SS + qg)) * DD + h * HD;
  bf16x8 qB[4];
#pragma unroll
  for (int ks = 0; ks < 4; ++ks)
    qB[ks] = *(const bf16x8*)(qptr + ks * 16 + hi8);

  // ones A-frag for the lsum MFMA
  bf16x8 ones;
#pragma unroll
  for (int i = 0; i < 8; ++i) ones[i] = (bf16)1.0f;

  // 4 shared fragment offsets (bytes): row part + XOR-permuted chunk.
  int off[4];
#pragma unroll
  for (int x = 0; x < 4; ++x)
    off[x] = l31 * 128 + (((2 * x + hi) ^ (l31 & 7)) * 16);

  // staging geometry (global_load_lds): 8 rows x 8 slots per call.
  const int lr  = lane >> 3;
  const int lc  = ((lane & 7) ^ lr) * 8;   // pre-swizzled source chunk
  const int r0  = w * 16 + lr;
  const bf16* kpA = K  + ((size_t)b * SS + r0) * DD + h * HD + lc;
  const bf16* kpB = kpA + (size_t)8 * DD;
  const bf16* vpA = Vt + ((size_t)bh * HD + r0) * SS + lc;
  const bf16* vpB = vpA + (size_t)8 * SS;
  bf16* kD0 = (bf16*)(smem + w * 2048);
  bf16* vD0 = (bf16*)(smem + 16384 + w * 2048);

  f32x16 acc[2] = {};
  f32x16 accL = {};

  // ---- prologue: mask*LOG2E -> Ms; stage tile 0 into buf 0 ----
  {
    const float* mbase = mask + b * SS;
    f32x4 m0 = *(const f32x4*)(mbase + tid * 8);
    f32x4 m1 = *(const f32x4*)(mbase + tid * 8 + 4);
    *(f32x4*)(smem + 32768 + tid * 32)      = m0 * LOG2E;
    *(f32x4*)(smem + 32768 + tid * 32 + 16) = m1 * LOG2E;
  }
  gload_lds16(kpA, kD0);
  gload_lds16(kpB, kD0 + 512);
  gload_lds16(vpA, vD0);
  gload_lds16(vpB, vD0 + 512);
  kpA += (size_t)64 * DD; kpB += (size_t)64 * DD;
  vpA += 64;              vpB += 64;
  drain_mem();
  __syncthreads();

  for (int t2 = 0; t2 < 16; ++t2) {
#pragma unroll
    for (int half = 0; half < 2; ++half) {
      const int t = t2 * 2 + half;
      const bool last = (t == 31);

      // ---- prefetch tile t+1 into buffer half^1 (async) ----
      if (!last) {
        bf16* kD = (bf16*)(smem + (half ^ 1) * 8192 + w * 2048);
        bf16* vD = (bf16*)(smem + 16384 + (half ^ 1) * 8192 + w * 2048);
        gload_lds16(kpA, kD);
        gload_lds16(kpB, kD + 512);
        gload_lds16(vpA, vD);
        gload_lds16(vpB, vD + 512);
        kpA += (size_t)64 * DD; kpB += (size_t)64 * DD;
        vpA += 64;              vpB += 64;
      }

      // ---- QK^T with mask*LOG2E as C-operand (Q pre-scaled) ----
      const char* mb = smem + (t * 256 + hi4 * 4);
      union { f32x16 v; f32x4 q[4]; } st[2];
#pragma unroll
      for (int kvb = 0; kvb < 2; ++kvb)
#pragma unroll
        for (int rg = 0; rg < 4; ++rg)
          st[kvb].q[rg] = *(const f32x4*)(mb + 32768 + kvb * 128 + rg * 32);

      __builtin_amdgcn_s_setprio(1);
#pragma unroll
      for (int kvb = 0; kvb < 2; ++kvb) {
#pragma unroll
        for (int ks = 0; ks < 4; ++ks) {
          bf16x8 ka = *(const bf16x8*)(smem + off[ks] + kvb * 4096 + half * 8192);
          st[kvb].v = MFMA32(ka, qB[ks], st[kvb].v);
        }
      }
      __builtin_amdgcn_s_setprio(0);

      // ---- V^T frags (issue early) ----
      bf16x8 va[2][4];
#pragma unroll
      for (int db = 0; db < 2; ++db)
#pragma unroll
        for (int sl = 0; sl < 4; ++sl)
          va[db][sl] = *(const bf16x8*)(smem + 16384 + off[sl] + db * 4096 + half * 8192);

      // ---- softmax: p = exp2(st) -- bare exp, no mul/add ----
#pragma unroll
      for (int kvb = 0; kvb < 2; ++kvb)
#pragma unroll
        for (int r = 0; r < 16; ++r)
          st[kvb].v[r] = fast_exp2(st[kvb].v[r]);

      // ---- P repack (pack + permlane32_swap), PV + lsum MFMAs ----
      __builtin_amdgcn_s_setprio(1);
#pragma unroll
      for (int kvb = 0; kvb < 2; ++kvb) {
#pragma unroll
        for (int s2 = 0; s2 < 2; ++s2) {
          unsigned L0 = pack2(st[kvb].v[8 * s2 + 0], st[kvb].v[8 * s2 + 1]);
          unsigned L1 = pack2(st[kvb].v[8 * s2 + 2], st[kvb].v[8 * s2 + 3]);
          unsigned H0 = pack2(st[kvb].v[8 * s2 + 4], st[kvb].v[8 * s2 + 5]);
          unsigned H1 = pack2(st[kvb].v[8 * s2 + 6], st[kvb].v[8 * s2 + 7]);
          swap32(L0, H0);
          swap32(L1, H1);
          union { unsigned u[4]; bf16x8 v; } pb;
          pb.u[0] = L0; pb.u[1] = L1; pb.u[2] = H0; pb.u[3] = H1;
          const int sl = kvb * 2 + s2;
          acc[0] = MFMA32(va[0][sl], pb.v, acc[0]);
          acc[1] = MFMA32(va[1][sl], pb.v, acc[1]);
          accL   = MFMA32(ones,      pb.v, accL);
        }
      }
      __builtin_amdgcn_s_setprio(0);

      drain_mem();       // explicit: prefetched gload_lds writes landed
      __syncthreads();
    }
  }

  // ---- accL[0] = full lsum for this lane's q column (col=l31, both hi) ----
  const float inv = 1.0f / accL[0];

  // ---- store ctx[qg][d] = acc^T * inv;  d = 32db + 8rg + 4hi + j ----
  float* op = out + ((size_t)(b * SS + qg)) * DD + h * HD;
#pragma unroll
  for (int db = 0; db < 2; ++db)
#pragma unroll
    for (int rg = 0; rg < 4; ++rg) {
      f32x4 v;
#pragma unroll
      for (int j = 0; j < 4; ++j) v[j] = acc[db][rg * 4 + j] * inv;
      *(f32x4*)(op + db * 32 + rg * 8 + hi4) = v;
    }
}

// ---------------------------------------------------------------------------
extern "C" void kernel_launch(void* const* d_in, const int* in_sizes, int n_in,
                              void* d_out, int out_size, void* d_ws, size_t ws_size,
                              hipStream_t stream) {
  const float* X    = (const float*)d_in[0];
  const float* mask = (const float*)d_in[1];
  const float* Wq   = (const float*)d_in[2];
  const float* bq   = (const float*)d_in[3];
  const float* Wk   = (const float*)d_in[4];
  const float* bk   = (const float*)d_in[5];
  const float* Wv   = (const float*)d_in[6];
  const float* bv   = (const float*)d_in[7];

  // workspace: Q | K | Vt (bf16, 16 MiB each)
  bf16* Qw = (bf16*)d_ws;
  bf16* Kw = Qw + (size_t)NX;
  bf16* Vt = Kw + (size_t)NX;
  // bf16 scratch for converted inputs lives in d_out (attn overwrites later).
  bf16* Xb = (bf16*)d_out;            // 16 MiB
  bf16* Wb = Xb + (size_t)NX;         // 6 MiB (Wq|Wk|Wv)

  cvt_bf16<<<(NX + 3 * NW) / 2048, 256, 0, stream>>>(X, Wq, Wk, Wv, Xb, Wb);

  dim3 g1((BB * SS) / 128, DD / 128, 3);
  qkv_gemm<<<g1, 256, 0, stream>>>(Xb, Wb, bq, bk, bv, Qw, Kw, Vt);

  dim3 g2(BB * HH, SS / 128);  // 64 x 16
  attn<<<g2, 256, 0, stream>>>(Qw, Kw, Vt, mask, (float*)d_out);
}